// Round 11
// baseline (7584.158 us; speedup 1.0000x reference)
//
#include <hip/hip_runtime.h>

// Problem constants (from setup_inputs: B=16, N=16384, D=128, S=N/4)
#define BATCH    16
#define NPTS     16384
#define NSAMP    4096
#define NTHREADS 1024
#define PPT      16
#define NCELL    1024
#define NWAVE    16

// DPP move (disabled lanes keep own value)
template<int CTRL, int RM>
__device__ __forceinline__ int dpp_i(int v) {
    return __builtin_amdgcn_update_dpp(v, v, CTRL, RM, 0xF, false);
}
// u64-key max step: hi = value bits (nonneg fp32), lo = (inv_orig<<10)|cell.
// max key == max value, then min original index. Exact tie-break, no branches.
template<int CTRL, int RM>
__device__ __forceinline__ void redk(unsigned& hi, unsigned& lo) {
    unsigned h2 = (unsigned)dpp_i<CTRL, RM>((int)hi);
    unsigned l2 = (unsigned)dpp_i<CTRL, RM>((int)lo);
    bool t = (h2 > hi) || (h2 == hi && l2 > lo);
    hi = t ? h2 : hi; lo = t ? l2 : lo;
}
// same, carrying the winner's coordinates along
template<int CTRL, int RM>
__device__ __forceinline__ void redk5(unsigned& hi, unsigned& lo,
                                      float& x, float& y, float& z) {
    unsigned h2 = (unsigned)dpp_i<CTRL, RM>((int)hi);
    unsigned l2 = (unsigned)dpp_i<CTRL, RM>((int)lo);
    float x2 = __int_as_float(dpp_i<CTRL, RM>(__float_as_int(x)));
    float y2 = __int_as_float(dpp_i<CTRL, RM>(__float_as_int(y)));
    float z2 = __int_as_float(dpp_i<CTRL, RM>(__float_as_int(z)));
    bool t = (h2 > hi) || (h2 == hi && l2 > lo);
    hi = t ? h2 : hi; lo = t ? l2 : lo;
    x = t ? x2 : x; y = t ? y2 : y; z = t ? z2 : z;
}

// order-preserving float -> uint map (IEEE total order)
__device__ __forceinline__ unsigned xform(float f) {
    unsigned u = __float_as_uint(f);
    return (u & 0x80000000u) ? ~u : (u | 0x80000000u);
}

// (segmented) bitonic sort in LDS; segbound = pow2 segment size
__device__ __forceinline__ void bitonic_lds(unsigned* key, int tid, int segbound) {
    for (int k = 2; k <= segbound; k <<= 1) {
        for (int j = k >> 1; j > 0; j >>= 1) {
            __syncthreads();
            #pragma unroll
            for (int m = 0; m < PPT; ++m) {
                int i = (m << 10) | tid;
                int l = i ^ j;
                if (l > i) {
                    unsigned a = key[i], c = key[l];
                    bool up = ((i & k) == 0);
                    if ((a > c) == up) { key[i] = c; key[l] = a; }
                }
            }
        }
    }
}

// -----------------------------------------------------------------------------
// FPS with MEMORY-RESIDENT state and COMPACTED recompute.
//  - Rank-split grid (x->8 slabs, y->64 cols, z->1024 cells of 16 pts) via 3
//    bitonic sorts. Cell boxes are tight and disjoint.
//  - pd lives in LDS; coords re-read from global (L2-resident). Owner thread
//    t keeps only its cell's bbox in registers and tests it per iteration.
//  - Tripped cells are ballot-compacted into a worklist; 16-lane groups
//    process ONLY those cells (rounds 5-10 recomputed 7 whole waves = ~20x
//    amplification because state was register-bound).
//  - Per-cell cached {max,argmax} u64 in s_ct + argmax coords in s_cc;
//    per-region slots rebuilt lazily (dirty waves only); global winner via
//    4-step u64 DPP reduce with coords carried in-register.
//  - Exactness: same fp32 ops/association as reference; box mindist is
//    fl-monotone below any member distance (plus 0.9999 guard); u64 keys
//    {val, ~orig} reproduce argmax first-original-index tie-break exactly.
// -----------------------------------------------------------------------------
__global__ __launch_bounds__(NTHREADS, 4) void fps_kernel(
    const float* __restrict__ xyz, int* __restrict__ sorted_idx)
{
    __shared__ float s_pd[NPTS];                   // 64KB (sort buffer in setup)
    __shared__ unsigned short s_ord[NPTS];         // 32KB orig idx per slot
    __shared__ unsigned long long s_ct[NCELL];     // 8KB {max_bits, key_lo}
    __shared__ float4 s_cc[NCELL];                 // 16KB cell argmax coords
    __shared__ unsigned long long s_slot[NWAVE];   // region max keys
    __shared__ float4 s_scc[NWAVE];                // region argmax coords
    __shared__ unsigned s_bitmap[NPTS / 32];       // 2KB
    __shared__ unsigned short s_wl[NCELL];         // 2KB worklist
    __shared__ int s_nw;
    __shared__ unsigned s_dirty[NWAVE];
    __shared__ int s_wt[NWAVE];

    const int tid  = threadIdx.x;
    const int lane = tid & 63;
    const int wid  = tid >> 6;
    const int sub  = tid & 15;
    const int gid  = tid >> 4;        // 16-lane group id, 0..63
    const int b    = blockIdx.x;
    const float* xb = xyz + (size_t)b * NPTS * 3;

    unsigned* skey = (unsigned*)s_pd;  // alias during setup only

    if (tid < NPTS / 32) s_bitmap[tid] = 0u;
    if (tid == 0) s_nw = 0;
    if (tid < NWAVE) s_dirty[tid] = 1u;

    // ---- partition sorts: x (16384), y within 2048, z within 256 ----
    #pragma unroll
    for (int k = 0; k < PPT; ++k) {
        int i = (tid << 4) + k;
        skey[i] = (xform(xb[3 * i]) & 0xFFFFC000u) | (unsigned)i;
    }
    bitonic_lds(skey, tid, NPTS);
    __syncthreads();
    #pragma unroll
    for (int m = 0; m < PPT; ++m) {
        int p = (m << 10) | tid;
        unsigned orig = skey[p] & 0x3FFFu;
        skey[p] = (xform(xb[3 * orig + 1]) & 0xFFFFC000u) | orig;
    }
    bitonic_lds(skey, tid, 2048);
    __syncthreads();
    #pragma unroll
    for (int m = 0; m < PPT; ++m) {
        int p = (m << 10) | tid;
        unsigned orig = skey[p] & 0x3FFFu;
        skey[p] = (xform(xb[3 * orig + 2]) & 0xFFFFC000u) | orig;
    }
    bitonic_lds(skey, tid, 256);
    __syncthreads();

    // ---- extract my cell's origs; release skey; init s_ord / s_pd ----
    unsigned my_o[PPT];
    #pragma unroll
    for (int k = 0; k < PPT; ++k) my_o[k] = skey[(tid << 4) + k] & 0x3FFFu;
    __syncthreads();
    #pragma unroll
    for (int k = 0; k < PPT; ++k) {
        s_ord[(tid << 4) + k] = (unsigned short)my_o[k];
        s_pd[(tid << 4) + k]  = 1e10f;    // BIG, matches reference init
    }

    // ---- owner bbox (registers) + init s_ct ----
    float bxl = 1e30f, byl = 1e30f, bzl = 1e30f;
    float bxh = -1e30f, byh = -1e30f, bzh = -1e30f;
    unsigned minorig = 0x3FFFu;
    #pragma unroll
    for (int k = 0; k < PPT; ++k) {
        unsigned g = my_o[k];
        float x = xb[3 * g], y = xb[3 * g + 1], z = xb[3 * g + 2];
        bxl = fminf(bxl, x); bxh = fmaxf(bxh, x);
        byl = fminf(byl, y); byh = fmaxf(byh, y);
        bzl = fminf(bzl, z); bzh = fmaxf(bzh, z);
        minorig = min(minorig, g);
    }
    s_ct[tid] = ((unsigned long long)0x501502F9u << 32) |   // bits(1e10f)
                (unsigned long long)(((minorig ^ 0x3FFFu) << 10) | (unsigned)tid);

    float cx = xb[0], cy = xb[1], cz = xb[2];   // initial farthest = index 0
    if (tid == 0) s_bitmap[0] = 1u;
    float tmaxf = 1e10f;
    __syncthreads();

    for (int s = 0; s < NSAMP - 1; ++s) {
        // ---- (a) owner test: exact skip proof (fl-monotone + guard) ----
        float tx = fmaxf(fmaxf(__fsub_rn(bxl, cx), __fsub_rn(cx, bxh)), 0.f);
        float ty = fmaxf(fmaxf(__fsub_rn(byl, cy), __fsub_rn(cy, byh)), 0.f);
        float tz = fmaxf(fmaxf(__fsub_rn(bzl, cz), __fsub_rn(cz, bzh)), 0.f);
        float md2 = 0.9999f * __fadd_rn(__fadd_rn(__fmul_rn(tx, tx),
                                                  __fmul_rn(ty, ty)),
                                        __fmul_rn(tz, tz));
        bool need = md2 < tmaxf;

        // ---- (b) ballot-compact tripped cells into the worklist ----
        unsigned long long bal = __ballot(need);
        int cnt = (int)__popcll(bal);
        int base = 0;
        if (lane == 0 && cnt) base = atomicAdd(&s_nw, cnt);
        base = __builtin_amdgcn_readlane(base, 0);
        if (need) {
            int pos = base + (int)__popcll(bal & ((1ull << lane) - 1ull));
            s_wl[pos] = (unsigned short)tid;
        }
        __syncthreads();   // b1: worklist complete
        int nw = s_nw;

        // ---- (c) 16-lane groups process only tripped cells ----
        for (int w = gid; w < nw; w += 64) {
            int cw   = (int)s_wl[w];
            int slot = (cw << 4) + sub;
            unsigned orig = (unsigned)s_ord[slot];
            float pdv = s_pd[slot];
            float x = xb[3 * orig], y = xb[3 * orig + 1], z = xb[3 * orig + 2];
            float dx = __fsub_rn(x, cx);
            float dy = __fsub_rn(y, cy);
            float dz = __fsub_rn(z, cz);
            float d  = __fadd_rn(__fadd_rn(__fmul_rn(dx, dx), __fmul_rn(dy, dy)),
                                 __fmul_rn(dz, dz));
            float nd = fminf(pdv, d);
            s_pd[slot] = nd;
            unsigned hi = __float_as_uint(nd);
            unsigned lo = ((orig ^ 0x3FFFu) << 10) | (unsigned)cw;
            float ax = x, ay = y, az = z;
            redk5<0x111, 0xF>(hi, lo, ax, ay, az);   // row_shr:1
            redk5<0x112, 0xF>(hi, lo, ax, ay, az);   // row_shr:2
            redk5<0x114, 0xF>(hi, lo, ax, ay, az);   // row_shr:4
            redk5<0x118, 0xF>(hi, lo, ax, ay, az);   // row_shr:8 -> lane sub=15
            if (sub == 15) {
                s_ct[cw] = ((unsigned long long)hi << 32) | lo;
                s_cc[cw] = make_float4(ax, ay, az, 0.f);
                s_dirty[cw >> 6] = 1u;
            }
        }
        __syncthreads();   // b2: pd / s_ct updates complete
        if (tid == 0) s_nw = 0;
        unsigned long long myct = s_ct[tid];   // prefetch next test's tmax

        // ---- (d) lazy per-region slot rebuild (dirty waves only) ----
        if (s_dirty[wid]) {
            int c0 = (wid << 6) | lane;
            unsigned long long cv = s_ct[c0];
            float4 cc = s_cc[c0];
            unsigned hi = (unsigned)(cv >> 32), lo = (unsigned)cv;
            float ax = cc.x, ay = cc.y, az = cc.z;
            redk5<0x111, 0xF>(hi, lo, ax, ay, az);
            redk5<0x112, 0xF>(hi, lo, ax, ay, az);
            redk5<0x114, 0xF>(hi, lo, ax, ay, az);
            redk5<0x118, 0xF>(hi, lo, ax, ay, az);
            redk5<0x142, 0xA>(hi, lo, ax, ay, az);   // row_bcast:15
            redk5<0x143, 0xC>(hi, lo, ax, ay, az);   // row_bcast:31 -> lane 63
            if (lane == 63) {
                s_slot[wid] = ((unsigned long long)hi << 32) | lo;
                s_scc[wid]  = make_float4(ax, ay, az, 0.f);
            }
            if (lane == 0) s_dirty[wid] = 0u;
        }
        __syncthreads();   // b3: slots published

        // ---- (e) global winner: 4-step u64 reduce over 16 slots ----
        unsigned long long sv = s_slot[lane & 15];
        float4 scc = s_scc[lane & 15];
        unsigned hi = (unsigned)(sv >> 32), lo = (unsigned)sv;
        float ax = scc.x, ay = scc.y, az = scc.z;
        redk5<0x111, 0xF>(hi, lo, ax, ay, az);
        redk5<0x112, 0xF>(hi, lo, ax, ay, az);
        redk5<0x114, 0xF>(hi, lo, ax, ay, az);
        redk5<0x118, 0xF>(hi, lo, ax, ay, az);       // lane 15 of each row
        unsigned wlo = (unsigned)__builtin_amdgcn_readlane((int)lo, 15);
        int g = (int)(((wlo >> 10) & 0x3FFFu) ^ 0x3FFFu);
        cx = __int_as_float(__builtin_amdgcn_readlane(__float_as_int(ax), 15));
        cy = __int_as_float(__builtin_amdgcn_readlane(__float_as_int(ay), 15));
        cz = __int_as_float(__builtin_amdgcn_readlane(__float_as_int(az), 15));
        if (tid == 0) s_bitmap[g >> 5] |= (1u << (g & 31));
        tmaxf = __uint_as_float((unsigned)(myct >> 32));
    }
    __syncthreads();

    // ---- tail: bitmap -> ascending index list via block prefix scan ----
    const int nwords = NPTS / 32;   // 512
    unsigned word = (tid < nwords) ? s_bitmap[tid] : 0u;
    int cnt = __popc(word);
    int inc = cnt;
    #pragma unroll
    for (int off = 1; off < 64; off <<= 1) {
        int n = __shfl_up(inc, off);
        if (lane >= off) inc += n;
    }
    if (lane == 63) s_wt[wid] = inc;
    __syncthreads();
    int bpos = inc - cnt;
    for (int w = 0; w < wid; ++w) bpos += s_wt[w];
    int* sb = sorted_idx + (size_t)b * NSAMP;
    int pos = bpos;
    unsigned wmask = word;
    while (wmask) {
        int k = __ffs(wmask) - 1;
        wmask &= wmask - 1;
        sb[pos++] = tid * 32 + k;
    }
}

// -----------------------------------------------------------------------------
// Gather kernel: one wave per sampled row.
//   out0 = new_xyz [B,S,3]; out1 = concat(xyz, points) [B,S,1,131]; out2 [B,S,128]
// -----------------------------------------------------------------------------
__global__ void gather_kernel(
    const float* __restrict__ xyz, const float* __restrict__ points,
    const float* __restrict__ pres, const int* __restrict__ sorted_idx,
    float* __restrict__ out0, float* __restrict__ out1, float* __restrict__ out2)
{
    int gw   = (int)((blockIdx.x * (unsigned)blockDim.x + threadIdx.x) >> 6);
    int lane = threadIdx.x & 63;
    if (gw >= BATCH * NSAMP) return;
    int b = gw >> 12;               // NSAMP == 4096
    int i = sorted_idx[gw];

    const float* xs = xyz    + ((size_t)b * NPTS + i) * 3;
    const float* ps = points + ((size_t)b * NPTS + i) * 128;
    const float* rs = pres   + ((size_t)b * NPTS + i) * 128;

    if (lane < 3) out0[(size_t)gw * 3 + lane] = xs[lane];

    float* o1 = out1 + (size_t)gw * 131;
    #pragma unroll
    for (int j = 0; j < 3; ++j) {
        int c = lane + 64 * j;
        if (c < 131) o1[c] = (c < 3) ? xs[c] : ps[c - 3];
    }

    const float2* r2 = (const float2*)rs;
    float2* o2 = (float2*)(out2 + (size_t)gw * 128);
    o2[lane] = r2[lane];
}

extern "C" void kernel_launch(void* const* d_in, const int* in_sizes, int n_in,
                              void* d_out, int out_size, void* d_ws, size_t ws_size,
                              hipStream_t stream)
{
    const float* xyz    = (const float*)d_in[0];
    const float* points = (const float*)d_in[1];
    const float* pres   = (const float*)d_in[2];

    float* out  = (float*)d_out;
    float* out0 = out;                                     // B*S*3
    float* out1 = out0 + (size_t)BATCH * NSAMP * 3;        // B*S*131
    float* out2 = out1 + (size_t)BATCH * NSAMP * 131;      // B*S*128

    int* sorted = (int*)d_ws;   // B*S ints = 256 KiB scratch

    fps_kernel<<<BATCH, NTHREADS, 0, stream>>>(xyz, sorted);

    int total_threads = BATCH * NSAMP * 64;   // one wave per sampled row
    int threads = 256;
    int blocks  = total_threads / threads;
    gather_kernel<<<blocks, threads, 0, stream>>>(xyz, points, pres, sorted,
                                                  out0, out1, out2);
}

// Round 12
// 6440.164 us; speedup vs baseline: 1.1776x; 1.1776x over previous
//
#include <hip/hip_runtime.h>

// Problem constants (from setup_inputs: B=16, N=16384, D=128, S=N/4)
#define BATCH    16
#define NPTS     16384
#define NSAMP    4096
#define NTHREADS 1024
#define PPT      16
#define NWAVE    16

typedef float f32x2 __attribute__((ext_vector_type(2)));

// packed f32 math: two independent IEEE-exact ops per instruction (VOP3P)
__device__ __forceinline__ f32x2 pk_add(f32x2 a, f32x2 b) {
    f32x2 r;
    asm("v_pk_add_f32 %0, %1, %2" : "=v"(r) : "v"(a), "v"(b));
    return r;
}
__device__ __forceinline__ f32x2 pk_mul(f32x2 a, f32x2 b) {
    f32x2 r;
    asm("v_pk_mul_f32 %0, %1, %2" : "=v"(r) : "v"(a), "v"(b));
    return r;
}

// DPP move helper (disabled lanes keep old value = own value)
template<int CTRL, int RM>
__device__ __forceinline__ float dpp_movf(float v) {
    return __int_as_float(__builtin_amdgcn_update_dpp(
        __float_as_int(v), __float_as_int(v), CTRL, RM, 0xF, false));
}

__device__ __forceinline__ float wave_max64(float v) {
    v = fmaxf(v, dpp_movf<0x111, 0xF>(v));   // row_shr:1
    v = fmaxf(v, dpp_movf<0x112, 0xF>(v));   // row_shr:2
    v = fmaxf(v, dpp_movf<0x114, 0xF>(v));   // row_shr:4
    v = fmaxf(v, dpp_movf<0x118, 0xF>(v));   // row_shr:8
    v = fmaxf(v, dpp_movf<0x142, 0xA>(v));   // row_bcast:15
    v = fmaxf(v, dpp_movf<0x143, 0xC>(v));   // row_bcast:31 -> lane 63 = max
    return v;
}

// order-preserving float -> uint map (IEEE total order)
__device__ __forceinline__ unsigned xform(float f) {
    unsigned u = __float_as_uint(f);
    return (u & 0x80000000u) ? ~u : (u | 0x80000000u);
}

// (segmented) bitonic sort of s_key in LDS; segbound = pow2 segment size
__device__ __forceinline__ void bitonic_lds(unsigned* s_key, int tid, int segbound) {
    for (int k = 2; k <= segbound; k <<= 1) {
        for (int j = k >> 1; j > 0; j >>= 1) {
            __syncthreads();
            #pragma unroll
            for (int m = 0; m < PPT; ++m) {
                int i = (m << 10) | tid;
                int l = i ^ j;
                if (l > i) {
                    unsigned a = s_key[i], c2 = s_key[l];
                    bool up = ((i & k) == 0);
                    if ((a > c2) == up) { s_key[i] = c2; s_key[l] = a; }
                }
            }
        }
    }
}

// -----------------------------------------------------------------------------
// FPS, rank-split grid (8x8x16 cells of 16 pts) + per-cell exact pruning
// (round-9 skeleton, best so far) + PACKED-F32 recompute:
//  - v_pk_add_f32/v_pk_mul_f32 process 2 points/instr. Exactness: pk ops are
//    two independent IEEE f32 ops; a-b computed as a+(-b) (bitwise equal);
//    association (xx+yy)+zz preserved per half.
//  - argmax index recovered AFTER the loop (first-match descending scan ==
//    smallest k == smallest original index, since k-order = orig-order).
//  - Everything else identical to round 9: owner-register state, one barrier,
//    parity slots, per-wave candidate cache, DPP phase C.
// -----------------------------------------------------------------------------
__global__ __launch_bounds__(NTHREADS, 4) void fps_kernel(
    const float* __restrict__ xyz, int* __restrict__ sorted_idx)
{
    __shared__ unsigned s_key[NPTS];                 // 64 KiB
    __shared__ unsigned s_bitmap[NPTS / 32];         // 2 KiB
    __shared__ unsigned long long s_slot[2][NWAVE];  // parity {max_bits, orig}
    __shared__ float s_ccf[2][NWAVE * 3];            // parity candidate coords
    __shared__ int s_wt[NWAVE];                      // tail scan totals

    const int tid  = threadIdx.x;
    const int lane = tid & 63;
    const int wid  = tid >> 6;
    const int b    = blockIdx.x;

    if (tid < NPTS / 32) s_bitmap[tid] = 0u;

    const float* xb = xyz + (size_t)b * NPTS * 3;

    // ---- partition sort 1: by x (full 16384) ----
    #pragma unroll
    for (int k = 0; k < PPT; ++k) {
        int i = (tid << 4) + k;
        s_key[i] = (xform(xb[3 * i]) & 0xFFFFC000u) | (unsigned)i;
    }
    bitonic_lds(s_key, tid, NPTS);
    __syncthreads();

    // ---- sort 2: by y within 8 x-slabs of 2048 ----
    #pragma unroll
    for (int m = 0; m < PPT; ++m) {
        int p = (m << 10) | tid;
        unsigned orig = s_key[p] & 0x3FFFu;
        s_key[p] = (xform(xb[3 * orig + 1]) & 0xFFFFC000u) | orig;
    }
    bitonic_lds(s_key, tid, 2048);
    __syncthreads();

    // ---- sort 3: by z within 64 columns of 256 ----
    #pragma unroll
    for (int m = 0; m < PPT; ++m) {
        int p = (m << 10) | tid;
        unsigned orig = s_key[p] & 0x3FFFu;
        s_key[p] = (xform(xb[3 * orig + 2]) & 0xFFFFC000u) | orig;
    }
    bitonic_lds(s_key, tid, 256);
    __syncthreads();

    // ---- per-thread cell: extract origs, in-register sort ascending ----
    unsigned o[PPT];
    #pragma unroll
    for (int k = 0; k < PPT; ++k) o[k] = s_key[(tid << 4) + k] & 0x3FFFu;
    #pragma unroll
    for (int r = 0; r < 16; ++r) {
        #pragma unroll
        for (int i = (r & 1); i + 1 < PPT; i += 2) {
            unsigned lo = min(o[i], o[i + 1]);
            unsigned hi = max(o[i], o[i + 1]);
            o[i] = lo; o[i + 1] = hi;
        }
    }
    #pragma unroll
    for (int k = 0; k < PPT; ++k) s_key[(tid << 4) + k] = o[k];

    // ---- gather coords into f32x2 pairs; tight cell bbox; init pd/tmax ----
    f32x2 px2[8], py2[8], pz2[8], pd2[8];
    float bxl = 1e30f, byl = 1e30f, bzl = 1e30f;
    float bxh = -1e30f, byh = -1e30f, bzh = -1e30f;
    #pragma unroll
    for (int k = 0; k < PPT; ++k) {
        int g = (int)o[k];
        float x = xb[3 * g], y = xb[3 * g + 1], z = xb[3 * g + 2];
        if (k & 1) { px2[k >> 1].y = x; py2[k >> 1].y = y; pz2[k >> 1].y = z; }
        else       { px2[k >> 1].x = x; py2[k >> 1].x = y; pz2[k >> 1].x = z; }
        bxl = fminf(bxl, x); bxh = fmaxf(bxh, x);
        byl = fminf(byl, y); byh = fmaxf(byh, y);
        bzl = fminf(bzl, z); bzh = fmaxf(bzh, z);
    }
    #pragma unroll
    for (int j = 0; j < 8; ++j) pd2[j] = (f32x2){1e10f, 1e10f};
    float tmax = 1e10f;

    // cached per-wave candidate (uniform); published while dirty
    float mval = 1e10f, mcx = 0.f, mcy = 0.f, mcz = 0.f;
    int   morig = 0, dirty = 0;

    float cx = xb[0], cy = xb[1], cz = xb[2];   // initial farthest = index 0
    if (tid == 0) s_bitmap[0] = 1u;
    __syncthreads();

    for (int s = 0; s < NSAMP - 1; ++s) {
        const int p = s & 1;

        // ---- per-thread exact skip test (tight cell box) ----
        float tx = fmaxf(fmaxf(__fsub_rn(bxl, cx), __fsub_rn(cx, bxh)), 0.f);
        float ty = fmaxf(fmaxf(__fsub_rn(byl, cy), __fsub_rn(cy, byh)), 0.f);
        float tz = fmaxf(fmaxf(__fsub_rn(bzl, cz), __fsub_rn(cz, bzh)), 0.f);
        float md2 = 0.9999f * __fadd_rn(__fadd_rn(__fmul_rn(tx, tx),
                                                  __fmul_rn(ty, ty)),
                                        __fmul_rn(tz, tz));
        if (__ballot(md2 < tmax) != 0ull) {   // recompute whole wave (packed)
            f32x2 ncx2 = (f32x2){-cx, -cx};
            f32x2 ncy2 = (f32x2){-cy, -cy};
            f32x2 ncz2 = (f32x2){-cz, -cz};
            float bv = -1.0f;
            #pragma unroll
            for (int j = 0; j < 8; ++j) {
                f32x2 dx = pk_add(px2[j], ncx2);   // == px - cx (IEEE exact)
                f32x2 dy = pk_add(py2[j], ncy2);
                f32x2 dz = pk_add(pz2[j], ncz2);
                f32x2 xx = pk_mul(dx, dx);
                f32x2 yy = pk_mul(dy, dy);
                f32x2 ss = pk_add(xx, yy);
                f32x2 zz = pk_mul(dz, dz);
                f32x2 dd = pk_add(ss, zz);         // (xx+yy)+zz association
                float n0 = fminf(pd2[j].x, dd.x);
                float n1 = fminf(pd2[j].y, dd.y);
                pd2[j].x = n0; pd2[j].y = n1;
                bv = fmaxf(bv, fmaxf(n0, n1));
            }
            tmax = bv;
            // argmax recovery: smallest k with pd==bv (k-order == orig-order)
            int bk = 0;
            #pragma unroll
            for (int j = 7; j >= 0; --j) {
                if (pd2[j].y == bv) bk = 2 * j + 1;
                if (pd2[j].x == bv) bk = 2 * j;
            }
            int bo_mine = (int)s_key[(tid << 4) + bk];

            float wv = wave_max64(bv);
            int   mb = __builtin_amdgcn_readlane(__float_as_int(wv), 63);
            float mw = __int_as_float(mb);
            unsigned long long mk = __ballot(bv == mw);
            int sl, bo;
            if (__popcll(mk) == 1) {                   // unique max lane
                sl = __ffsll(mk) - 1;
                bo = __builtin_amdgcn_readlane(bo_mine, sl);
            } else {                                   // rare: min orig over ties
                unsigned long long t = mk;
                bo = 0x7FFFFFFF; sl = 0;
                while (t) {
                    int l = __ffsll(t) - 1; t &= t - 1;
                    int b2 = __builtin_amdgcn_readlane(bo_mine, l);
                    if (b2 < bo) { bo = b2; sl = l; }
                }
            }
            // candidate coords: every lane extracts its own, take lane sl's
            float ax = px2[0].x, ay = py2[0].x, az = pz2[0].x;
            #pragma unroll
            for (int j = 0; j < 8; ++j) {
                if (bk == 2 * j)     { ax = px2[j].x; ay = py2[j].x; az = pz2[j].x; }
                if (bk == 2 * j + 1) { ax = px2[j].y; ay = py2[j].y; az = pz2[j].y; }
            }
            mcx = __int_as_float(__builtin_amdgcn_readlane(__float_as_int(ax), sl));
            mcy = __int_as_float(__builtin_amdgcn_readlane(__float_as_int(ay), sl));
            mcz = __int_as_float(__builtin_amdgcn_readlane(__float_as_int(az), sl));
            mval = mw; morig = bo; dirty = 2;
        }

        if (dirty > 0) {                   // publish cached candidate (both parities)
            if (lane == 0) {
                s_slot[p][wid] =
                    ((unsigned long long)(unsigned)__float_as_int(mval) << 32) |
                    (unsigned)morig;
                s_ccf[p][wid * 3 + 0] = mcx;
                s_ccf[p][wid * 3 + 1] = mcy;
                s_ccf[p][wid * 3 + 2] = mcz;
            }
            dirty -= 1;
        }

        __syncthreads();   // the ONLY barrier per iteration

        // ---- block winner over 16 wave slots; coords read in parallel ----
        unsigned long long key = s_slot[p][lane & 15];
        float cf = s_ccf[p][lane < 48 ? lane : 0];
        float cv = __int_as_float((int)(key >> 32));
        int   ci = (int)(unsigned)key;
        float rv = cv;
        rv = fmaxf(rv, dpp_movf<0x111, 0xF>(rv));
        rv = fmaxf(rv, dpp_movf<0x112, 0xF>(rv));
        rv = fmaxf(rv, dpp_movf<0x114, 0xF>(rv));
        rv = fmaxf(rv, dpp_movf<0x118, 0xF>(rv));  // lane 15 of row = max
        int   gmb = __builtin_amdgcn_readlane(__float_as_int(rv), 15);
        float gm  = __int_as_float(gmb);
        unsigned long long m2 = __ballot(cv == gm);
        int w, g;
        if (__popcll(m2) == 4) {                   // unique winning wave
            w = __ffsll(m2) - 1;
            g = __builtin_amdgcn_readlane(ci, w);
        } else {                                   // rare: min orig across waves
            unsigned long long t = m2 & 0xFFFFull;
            g = 0x7FFFFFFF; w = 0;
            while (t) {
                int l = __ffsll(t) - 1; t &= t - 1;
                int g2 = __builtin_amdgcn_readlane(ci, l);
                if (g2 < g) { g = g2; w = l; }
            }
        }
        cx = __int_as_float(__builtin_amdgcn_readlane(__float_as_int(cf), w * 3 + 0));
        cy = __int_as_float(__builtin_amdgcn_readlane(__float_as_int(cf), w * 3 + 1));
        cz = __int_as_float(__builtin_amdgcn_readlane(__float_as_int(cf), w * 3 + 2));

        if (tid == 0) s_bitmap[g >> 5] |= (1u << (g & 31));
    }
    __syncthreads();

    // ---- tail: bitmap -> ascending index list via block prefix scan ----
    const int nwords = NPTS / 32;   // 512
    unsigned word = (tid < nwords) ? s_bitmap[tid] : 0u;
    int cnt = __popc(word);
    int inc = cnt;
    #pragma unroll
    for (int off = 1; off < 64; off <<= 1) {
        int n = __shfl_up(inc, off);
        if (lane >= off) inc += n;
    }
    if (lane == 63) s_wt[wid] = inc;
    __syncthreads();
    int base = inc - cnt;
    for (int w = 0; w < wid; ++w) base += s_wt[w];
    int* sb = sorted_idx + (size_t)b * NSAMP;
    int pos = base;
    unsigned wmask = word;
    while (wmask) {
        int k = __ffs(wmask) - 1;
        wmask &= wmask - 1;
        sb[pos++] = tid * 32 + k;
    }
}

// -----------------------------------------------------------------------------
// Gather kernel: one wave per sampled row.
//   out0 = new_xyz [B,S,3]; out1 = concat(xyz, points) [B,S,1,131]; out2 [B,S,128]
// -----------------------------------------------------------------------------
__global__ void gather_kernel(
    const float* __restrict__ xyz, const float* __restrict__ points,
    const float* __restrict__ pres, const int* __restrict__ sorted_idx,
    float* __restrict__ out0, float* __restrict__ out1, float* __restrict__ out2)
{
    int gw   = (int)((blockIdx.x * (unsigned)blockDim.x + threadIdx.x) >> 6);
    int lane = threadIdx.x & 63;
    if (gw >= BATCH * NSAMP) return;
    int b = gw >> 12;               // NSAMP == 4096
    int i = sorted_idx[gw];

    const float* xs = xyz    + ((size_t)b * NPTS + i) * 3;
    const float* ps = points + ((size_t)b * NPTS + i) * 128;
    const float* rs = pres   + ((size_t)b * NPTS + i) * 128;

    if (lane < 3) out0[(size_t)gw * 3 + lane] = xs[lane];

    float* o1 = out1 + (size_t)gw * 131;
    #pragma unroll
    for (int j = 0; j < 3; ++j) {
        int c = lane + 64 * j;
        if (c < 131) o1[c] = (c < 3) ? xs[c] : ps[c - 3];
    }

    const float2* r2 = (const float2*)rs;
    float2* o2 = (float2*)(out2 + (size_t)gw * 128);
    o2[lane] = r2[lane];
}

extern "C" void kernel_launch(void* const* d_in, const int* in_sizes, int n_in,
                              void* d_out, int out_size, void* d_ws, size_t ws_size,
                              hipStream_t stream)
{
    const float* xyz    = (const float*)d_in[0];
    const float* points = (const float*)d_in[1];
    const float* pres   = (const float*)d_in[2];

    float* out  = (float*)d_out;
    float* out0 = out;                                     // B*S*3
    float* out1 = out0 + (size_t)BATCH * NSAMP * 3;        // B*S*131
    float* out2 = out1 + (size_t)BATCH * NSAMP * 131;      // B*S*128

    int* sorted = (int*)d_ws;   // B*S ints = 256 KiB scratch

    fps_kernel<<<BATCH, NTHREADS, 0, stream>>>(xyz, sorted);

    int total_threads = BATCH * NSAMP * 64;   // one wave per sampled row
    int threads = 256;
    int blocks  = total_threads / threads;
    gather_kernel<<<blocks, threads, 0, stream>>>(xyz, points, pres, sorted,
                                                  out0, out1, out2);
}